// Round 2
// baseline (645.288 us; speedup 1.0000x reference)
//
#include <hip/hip_runtime.h>
#include <cstdint>
#include <cstddef>

// FourierAttention: B=4 L=8192 H=16 D=64, Ls=64 -> M=128, BH=64 batch-heads.
// scores[m,n] = sum_l q_l^T G' k_l, G' = Gre + i*Gim, lam = 1/32768.
// Algebra: Gre = lam*(32*I + E), E[d,dp] = [d parity == dp parity]
//   => Sre = lam*(32*Q.K^T + Pq.Pk^T), P = per-l even/odd sums.
// Gim[delta] = 0 for even delta; dense MFMA transform kept for Kim.
// A = softmax_n(|s|), Out[m,l,:] = sum_n A[m,n] V[n,l,:].

typedef short bf16x8 __attribute__((ext_vector_type(8)));
typedef float f32x4 __attribute__((ext_vector_type(4)));

__device__ __forceinline__ ushort f2bf(float f) {
    union { float f; uint32_t u; } v; v.f = f;
    uint32_t r = (v.u + 0x7FFFu + ((v.u >> 16) & 1u)) >> 16;
    return (ushort)r;
}

__device__ __forceinline__ float bf2f(ushort h) {
    union { uint32_t u; float f; } v; v.u = ((uint32_t)h) << 16;
    return v.f;
}

// Gim tables, NT layout for MFMA B-operand: Gim[d*64+dp], hi/lo bf16 split.
__global__ void k_gmat(ushort* __restrict__ GimH, ushort* __restrict__ GimL) {
    const float lam = 1.0f / 32768.0f;
    const float c = 3.14159265358979323846f / 32.0f;   // 2*pi/64
    for (int e = threadIdx.x + blockIdx.x * blockDim.x; e < 4096; e += blockDim.x * gridDim.x) {
        int d = e >> 6, dp = e & 63;
        int delta = d - dp;
        float im = 0.f;
        for (int k = 0; k <= 32; ++k) {
            int r = ((k * delta) % 64 + 64) % 64;
            im -= sinf(c * (float)r);
        }
        im *= lam;
        ushort ih = f2bf(im);
        GimH[e] = ih;
        GimL[e] = f2bf(im - bf2f(ih));
    }
}

#define PSCALE 0.17677669529663687f   // 1/sqrt(32)

// Q[b, m*64+l, h, d] fp32 -> Qf[bh][m][4224]: cols 0..4095 bf16(Q), cols 4096+2l+p parity sums
__global__ __launch_bounds__(256) void k_prep_q(const float* __restrict__ Q, ushort* __restrict__ Qf) {
    int t = threadIdx.x;
    for (int it = 0; it < 8; ++it) {
        int g = blockIdx.x * 8 + it;
        int bh = g >> 7, m = g & 127;
        int b = bh >> 4, h = bh & 15;
        const float* qbase = Q + ((size_t)(b * 8192 + m * 64)) * 1024 + h * 64;
        ushort* obase = Qf + ((size_t)bh * 128 + m) * 4224;
        #pragma unroll
        for (int k = 0; k < 4; ++k) {
            int idx = k * 256 + t;
            int l = idx >> 4, d4 = (idx & 15) * 4;
            float4 v = *(const float4*)(qbase + (size_t)l * 1024 + d4);
            ushort4 o; o.x = f2bf(v.x); o.y = f2bf(v.y); o.z = f2bf(v.z); o.w = f2bf(v.w);
            *(ushort4*)(obase + l * 64 + d4) = o;
            float pe = v.x + v.z, po = v.y + v.w;
            pe += __shfl_xor(pe, 1); po += __shfl_xor(po, 1);
            pe += __shfl_xor(pe, 2); po += __shfl_xor(po, 2);
            pe += __shfl_xor(pe, 4); po += __shfl_xor(po, 4);
            pe += __shfl_xor(pe, 8); po += __shfl_xor(po, 8);
            if ((t & 15) == 0) {
                ushort2 pp; pp.x = f2bf(pe * PSCALE); pp.y = f2bf(po * PSCALE);
                *(ushort2*)(obase + 4096 + 2 * l) = pp;
            }
        }
    }
}

// K -> Kf (plain bf16 + parity cols, [bh][n][4224]) and Kim = Gim.K ([bh][n][4096]).
// 1024 blocks x 8 segments; Kim packed through LDS for coalesced stores.
__global__ __launch_bounds__(256) void k_prep_k(const float* __restrict__ K,
                                                const ushort* __restrict__ GimH,
                                                const ushort* __restrict__ GimL,
                                                ushort* __restrict__ Kf, ushort* __restrict__ Kim) {
    __shared__ ushort kb[64 * 72];
    int t = threadIdx.x;
    int lane = t & 63, wave = t >> 6;
    int wm = wave >> 1, wn = wave & 1;
    int row16 = lane & 15, quad = lane >> 4;
    int rrow = t >> 2, rcol = (t & 3) * 16;

    bf16x8 gih[2][2], gil[2][2];   // [nt][kk], constant per wave
    #pragma unroll
    for (int nt = 0; nt < 2; ++nt)
        #pragma unroll
        for (int kk = 0; kk < 2; ++kk) {
            int off = (wn * 32 + nt * 16 + row16) * 64 + kk * 32 + quad * 8;
            gih[nt][kk] = *(const bf16x8*)(GimH + off);
            gil[nt][kk] = *(const bf16x8*)(GimL + off);
        }

    for (int it = 0; it < 8; ++it) {
        int g = blockIdx.x * 8 + it;
        int bh = g >> 7, n = g & 127;
        int b = bh >> 4, h = bh & 15;
        const float* kbase = K + ((size_t)(b * 8192 + n * 64 + rrow)) * 1024 + h * 64 + rcol;
        ushort* kfrow = Kf + ((size_t)bh * 128 + n) * 4224;
        float pe = 0.f, po = 0.f;
        #pragma unroll
        for (int c = 0; c < 4; ++c) {
            float4 v = *(const float4*)(kbase + c * 4);
            ushort4 o; o.x = f2bf(v.x); o.y = f2bf(v.y); o.z = f2bf(v.z); o.w = f2bf(v.w);
            *(ushort4*)&kb[rrow * 72 + rcol + c * 4] = o;
            *(ushort4*)(kfrow + rrow * 64 + rcol + c * 4) = o;
            pe += v.x + v.z; po += v.y + v.w;
        }
        pe += __shfl_xor(pe, 1); po += __shfl_xor(po, 1);
        pe += __shfl_xor(pe, 2); po += __shfl_xor(po, 2);
        if ((t & 3) == 0) {
            ushort2 pp; pp.x = f2bf(pe * PSCALE); pp.y = f2bf(po * PSCALE);
            *(ushort2*)(kfrow + 4096 + 2 * rrow) = pp;
        }
        __syncthreads();

        f32x4 acc[2][2] = {};
        #pragma unroll
        for (int kk = 0; kk < 2; ++kk) {
            bf16x8 a[2];
            #pragma unroll
            for (int mt = 0; mt < 2; ++mt)
                a[mt] = *(const bf16x8*)&kb[(wm * 32 + mt * 16 + row16) * 72 + kk * 32 + quad * 8];
            #pragma unroll
            for (int mt = 0; mt < 2; ++mt)
                #pragma unroll
                for (int nt = 0; nt < 2; ++nt) {
                    acc[mt][nt] = __builtin_amdgcn_mfma_f32_16x16x32_bf16(a[mt], gih[nt][kk], acc[mt][nt], 0, 0, 0);
                    acc[mt][nt] = __builtin_amdgcn_mfma_f32_16x16x32_bf16(a[mt], gil[nt][kk], acc[mt][nt], 0, 0, 0);
                }
        }
        __syncthreads();
        #pragma unroll
        for (int mt = 0; mt < 2; ++mt)
            #pragma unroll
            for (int nt = 0; nt < 2; ++nt)
                #pragma unroll
                for (int i = 0; i < 4; ++i)
                    kb[(wm * 32 + mt * 16 + quad * 4 + i) * 72 + wn * 32 + nt * 16 + row16] = f2bf(acc[mt][nt][i]);
        __syncthreads();
        ushort* kimrow = Kim + ((size_t)bh * 128 + n) * 4096;
        *(uint4*)(kimrow + rrow * 64 + rcol)     = *(uint4*)&kb[rrow * 72 + rcol];
        *(uint4*)(kimrow + rrow * 64 + rcol + 8) = *(uint4*)&kb[rrow * 72 + rcol + 8];
        __syncthreads();
    }
}

// Sre = (32*lam)*(Qf.Kf^T incl parity cols), Sim = Qf.Kim^T.  K=4224/4096.
// 64m x 64n tile per block, grid (4, 64); register-prefetch double buffer.
__global__ __launch_bounds__(256) void k_scores(const ushort* __restrict__ Qf,
                                                const ushort* __restrict__ Kf,
                                                const ushort* __restrict__ Kim,
                                                float* __restrict__ Sre, float* __restrict__ Sim) {
    __shared__ ushort qt[64 * 72], ret[64 * 72], imt[64 * 72];
    int bh = blockIdx.y;
    int mh = blockIdx.x >> 1, nh = blockIdx.x & 1;
    int m0 = mh * 64, n0 = nh * 64;
    int t = threadIdx.x;
    int lane = t & 63, wave = t >> 6;
    int wm = wave >> 1, wn = wave & 1;
    int row16 = lane & 15, quad = lane >> 4;
    const ushort* qg = Qf + ((size_t)bh * 128 + m0) * 4224;
    const ushort* rg = Kf + ((size_t)bh * 128 + n0) * 4224;
    const ushort* ig = Kim + ((size_t)bh * 128 + n0) * 4096;
    uint4 rq[2], rk[2], ri[2];
    #pragma unroll
    for (int p = 0; p < 2; ++p) {
        int idx = p * 256 + t;
        int row = idx >> 3, ch = idx & 7;
        rq[p] = *(const uint4*)(qg + (size_t)row * 4224 + ch * 8);
        rk[p] = *(const uint4*)(rg + (size_t)row * 4224 + ch * 8);
        ri[p] = *(const uint4*)(ig + (size_t)row * 4096 + ch * 8);
    }
    f32x4 accre[2][2] = {};
    f32x4 accim[2][2] = {};
    for (int kt = 0; kt < 66; ++kt) {
        bool haveim = kt < 64;
        #pragma unroll
        for (int p = 0; p < 2; ++p) {
            int idx = p * 256 + t;
            int row = idx >> 3, ch = idx & 7;
            int lo = row * 72 + ch * 8;
            *(uint4*)&qt[lo] = rq[p];
            *(uint4*)&ret[lo] = rk[p];
            if (haveim) *(uint4*)&imt[lo] = ri[p];
        }
        __syncthreads();
        if (kt + 1 < 66) {
            int j0 = (kt + 1) * 64;
            #pragma unroll
            for (int p = 0; p < 2; ++p) {
                int idx = p * 256 + t;
                int row = idx >> 3, ch = idx & 7;
                rq[p] = *(const uint4*)(qg + (size_t)row * 4224 + j0 + ch * 8);
                rk[p] = *(const uint4*)(rg + (size_t)row * 4224 + j0 + ch * 8);
                if (kt + 1 < 64) ri[p] = *(const uint4*)(ig + (size_t)row * 4096 + j0 + ch * 8);
            }
        }
        #pragma unroll
        for (int kk = 0; kk < 2; ++kk) {
            bf16x8 a[2], br[2], bi[2];
            #pragma unroll
            for (int mt = 0; mt < 2; ++mt)
                a[mt] = *(const bf16x8*)&qt[(wm * 32 + mt * 16 + row16) * 72 + kk * 32 + quad * 8];
            #pragma unroll
            for (int nt = 0; nt < 2; ++nt) {
                br[nt] = *(const bf16x8*)&ret[(wn * 32 + nt * 16 + row16) * 72 + kk * 32 + quad * 8];
                if (haveim) bi[nt] = *(const bf16x8*)&imt[(wn * 32 + nt * 16 + row16) * 72 + kk * 32 + quad * 8];
            }
            #pragma unroll
            for (int mt = 0; mt < 2; ++mt)
                #pragma unroll
                for (int nt = 0; nt < 2; ++nt) {
                    accre[mt][nt] = __builtin_amdgcn_mfma_f32_16x16x32_bf16(a[mt], br[nt], accre[mt][nt], 0, 0, 0);
                    if (haveim)
                        accim[mt][nt] = __builtin_amdgcn_mfma_f32_16x16x32_bf16(a[mt], bi[nt], accim[mt][nt], 0, 0, 0);
                }
        }
        __syncthreads();
    }
    float* sre = Sre + (size_t)bh * 16384;
    float* sim = Sim + (size_t)bh * 16384;
    #pragma unroll
    for (int mt = 0; mt < 2; ++mt)
        #pragma unroll
        for (int nt = 0; nt < 2; ++nt)
            #pragma unroll
            for (int i = 0; i < 4; ++i) {
                int r = m0 + wm * 32 + mt * 16 + quad * 4 + i;
                int c = n0 + wn * 32 + nt * 16 + row16;
                sre[r * 128 + c] = accre[mt][nt][i] * 0.0009765625f;   // 32/32768
                sim[r * 128 + c] = accim[mt][nt][i];
            }
}

// logits = |s|; softmax over n (128). One wave per row, 2 cols/lane, no LDS.
__global__ __launch_bounds__(256) void k_softmax(const float* __restrict__ Sre,
                                                 const float* __restrict__ Sim,
                                                 ushort* __restrict__ A) {
    int t = threadIdx.x;
    int lane = t & 63, wave = t >> 6;
    for (int it = 0; it < 4; ++it) {
        int row = blockIdx.x * 16 + it * 4 + wave;
        size_t off = (size_t)row * 128 + lane * 2;
        float2 re = *(const float2*)(Sre + off);
        float2 im = *(const float2*)(Sim + off);
        float lg0 = sqrtf(re.x * re.x + im.x * im.x);
        float lg1 = sqrtf(re.y * re.y + im.y * im.y);
        float mx = fmaxf(lg0, lg1);
        for (int o = 32; o > 0; o >>= 1) mx = fmaxf(mx, __shfl_xor(mx, o));
        float e0 = expf(lg0 - mx), e1 = expf(lg1 - mx);
        float s = e0 + e1;
        for (int o = 32; o > 0; o >>= 1) s += __shfl_xor(s, o);
        float inv = 1.0f / s;
        ushort2 o2; o2.x = f2bf(e0 * inv); o2.y = f2bf(e1 * inv);
        *(ushort2*)(A + off) = o2;
    }
}

// V[b, n*64+l, h, d] -> Vt[bh][l*64+d][n] bf16; 2048 blocks x 4 l each.
__global__ __launch_bounds__(256) void k_vt(const float* __restrict__ V, ushort* __restrict__ Vt) {
    __shared__ float tile[64 * 68];
    int lg = blockIdx.x, nh = blockIdx.y, bh = blockIdx.z;
    int b = bh >> 4, h = bh & 15;
    int t = threadIdx.x;
    int n = t & 63, dq = t >> 6;
    int d = t >> 2, cq = t & 3;
    for (int it = 0; it < 4; ++it) {
        int l = lg * 4 + it;
        const float* vbase = V + ((size_t)(b * 8192 + (nh * 64 + n) * 64 + l)) * 1024 + h * 64;
        #pragma unroll
        for (int r = 0; r < 4; ++r) {
            int d0 = r * 16 + dq * 4;
            float4 v = *(const float4*)(vbase + d0);
            tile[(d0 + 0) * 68 + n] = v.x; tile[(d0 + 1) * 68 + n] = v.y;
            tile[(d0 + 2) * 68 + n] = v.z; tile[(d0 + 3) * 68 + n] = v.w;
        }
        __syncthreads();
        __align__(16) ushort u[16];
        #pragma unroll
        for (int i = 0; i < 16; ++i) u[i] = f2bf(tile[d * 68 + cq * 16 + i]);
        ushort* ob = Vt + ((size_t)bh * 4096 + l * 64 + d) * 128 + nh * 64 + cq * 16;
        *(uint4*)(ob) = *(uint4*)&u[0];
        *(uint4*)(ob + 8) = *(uint4*)&u[8];
        __syncthreads();
    }
}

// Out[m, j=(l,d)] = sum_n A[m][n] * Vt[j][n]; stage A once, loop 8 j-tiles.
__global__ __launch_bounds__(256) void k_mix(const ushort* __restrict__ A,
                                             const ushort* __restrict__ Vt,
                                             float* __restrict__ Out) {
    __shared__ ushort At[128 * 136], Vtl[64 * 136];
    int grp = blockIdx.x, bh = blockIdx.y;
    int b = bh >> 4, h = bh & 15;
    int t = threadIdx.x;
    int lane = t & 63, wave = t >> 6;
    int row16 = lane & 15, quad = lane >> 4;
    const ushort* ag = A + (size_t)bh * 16384;
    #pragma unroll
    for (int p = 0; p < 8; ++p) {
        int idx = p * 256 + t;
        int row = idx >> 4, ch = idx & 15;
        *(uint4*)&At[row * 136 + ch * 8] = *(const uint4*)(ag + row * 128 + ch * 8);
    }
    for (int jt8 = 0; jt8 < 8; ++jt8) {
        int jt = grp * 8 + jt8;
        int j0 = jt * 64;
        const ushort* vg = Vt + ((size_t)bh * 4096 + j0) * 128;
        __syncthreads();
        #pragma unroll
        for (int p = 0; p < 4; ++p) {
            int idx = p * 256 + t;
            int row = idx >> 4, ch = idx & 15;
            *(uint4*)&Vtl[row * 136 + ch * 8] = *(const uint4*)(vg + (size_t)row * 128 + ch * 8);
        }
        __syncthreads();
        f32x4 acc[2][4] = {};
        #pragma unroll
        for (int kk = 0; kk < 4; ++kk) {
            bf16x8 a[2], bv[4];
            #pragma unroll
            for (int mt = 0; mt < 2; ++mt)
                a[mt] = *(const bf16x8*)&At[(wave * 32 + mt * 16 + row16) * 136 + kk * 32 + quad * 8];
            #pragma unroll
            for (int j2 = 0; j2 < 4; ++j2)
                bv[j2] = *(const bf16x8*)&Vtl[(j2 * 16 + row16) * 136 + kk * 32 + quad * 8];
            #pragma unroll
            for (int mt = 0; mt < 2; ++mt)
                #pragma unroll
                for (int j2 = 0; j2 < 4; ++j2)
                    acc[mt][j2] = __builtin_amdgcn_mfma_f32_16x16x32_bf16(a[mt], bv[j2], acc[mt][j2], 0, 0, 0);
        }
        #pragma unroll
        for (int mt = 0; mt < 2; ++mt)
            #pragma unroll
            for (int j2 = 0; j2 < 4; ++j2)
                #pragma unroll
                for (int i = 0; i < 4; ++i) {
                    int m = wave * 32 + mt * 16 + quad * 4 + i;
                    int dd = j2 * 16 + row16;
                    Out[((size_t)(b * 8192 + m * 64 + jt)) * 1024 + h * 64 + dd] = acc[mt][j2][i];
                }
    }
}

extern "C" void kernel_launch(void* const* d_in, const int* in_sizes, int n_in,
                              void* d_out, int out_size, void* d_ws, size_t ws_size,
                              hipStream_t stream) {
    const float* Q = (const float*)d_in[0];
    const float* K = (const float*)d_in[1];
    const float* V = (const float*)d_in[2];
    float* Out = (float*)d_out;
    char* ws = (char*)d_ws;
    // ws layout (total ~206 MiB):
    ushort* GimH = (ushort*)ws;                                  // 8 KB
    ushort* GimL = GimH + 4096;                                  // 8 KB
    float* Sre  = (float*)(ws + 32768);                          // 4 MB
    float* Sim  = (float*)(ws + 32768 + 4194304);                // 4 MB
    ushort* A   = (ushort*)(ws + 32768 + 2 * 4194304);           // 2 MB
    ushort* Qf  = (ushort*)(ws + 32768 + 2 * 4194304 + 2097152); // 66 MB (rows 4224)
    ushort* Kf  = Qf + (size_t)64 * 128 * 4224;                  // 66 MB
    ushort* Kim = Kf + (size_t)64 * 128 * 4224;                  // 64 MB (rows 4096)
    ushort* Vt  = Qf;  // alias: Qf dead after k_scores

    k_gmat<<<16, 256, 0, stream>>>(GimH, GimL);
    k_prep_q<<<1024, 256, 0, stream>>>(Q, Qf);
    k_prep_k<<<1024, 256, 0, stream>>>(K, GimH, GimL, Kf, Kim);
    k_scores<<<dim3(4, 64), 256, 0, stream>>>(Qf, Kf, Kim, Sre, Sim);
    k_softmax<<<512, 256, 0, stream>>>(Sre, Sim, A);
    k_vt<<<dim3(16, 2, 64), 256, 0, stream>>>(V, Vt);
    k_mix<<<dim3(8, 64), 256, 0, stream>>>(A, Vt, Out);
}

// Round 3
// 572.640 us; speedup vs baseline: 1.1269x; 1.1269x over previous
//
#include <hip/hip_runtime.h>
#include <cstdint>
#include <cstddef>

// FourierAttention: B=4 L=8192 H=16 D=64, Ls=64 -> M=128, BH=64 batch-heads.
// scores[m,n] = sum_l q_l^T G' k_l, G' = Gre + i*Gim, lam = 1/32768.
// Algebra: Gre = lam*(32*I + E), E[d,dp] = [d parity == dp parity]
//   => Sre = lam*(32*Q.K^T + Pq.Pk^T), P = per-l even/odd sums.
// Gim[delta] = 0 for even delta; dense MFMA transform kept for Kim.
// A = softmax_n(|s|), Out[m,l,:] = sum_n A[m,n] V[n,l,:].

typedef short bf16x8 __attribute__((ext_vector_type(8)));
typedef float f32x4 __attribute__((ext_vector_type(4)));

__device__ __forceinline__ ushort f2bf(float f) {
    union { float f; uint32_t u; } v; v.f = f;
    uint32_t r = (v.u + 0x7FFFu + ((v.u >> 16) & 1u)) >> 16;
    return (ushort)r;
}

__device__ __forceinline__ float bf2f(ushort h) {
    union { uint32_t u; float f; } v; v.u = ((uint32_t)h) << 16;
    return v.f;
}

// Gim tables, NT layout for MFMA B-operand: Gim[d*64+dp], hi/lo bf16 split.
__global__ void k_gmat(ushort* __restrict__ GimH, ushort* __restrict__ GimL) {
    const float lam = 1.0f / 32768.0f;
    const float c = 3.14159265358979323846f / 32.0f;   // 2*pi/64
    for (int e = threadIdx.x + blockIdx.x * blockDim.x; e < 4096; e += blockDim.x * gridDim.x) {
        int d = e >> 6, dp = e & 63;
        int delta = d - dp;
        float im = 0.f;
        for (int k = 0; k <= 32; ++k) {
            int r = ((k * delta) % 64 + 64) % 64;
            im -= sinf(c * (float)r);
        }
        im *= lam;
        ushort ih = f2bf(im);
        GimH[e] = ih;
        GimL[e] = f2bf(im - bf2f(ih));
    }
}

#define PSCALE 0.17677669529663687f   // 1/sqrt(32)

// Q[b, m*64+l, h, d] fp32 -> Qf[bh][m][4224]: cols 0..4095 bf16(Q), cols 4096+2l+p parity sums
__global__ __launch_bounds__(256) void k_prep_q(const float* __restrict__ Q, ushort* __restrict__ Qf) {
    int t = threadIdx.x;
    for (int it = 0; it < 8; ++it) {
        int g = blockIdx.x * 8 + it;
        int bh = g >> 7, m = g & 127;
        int b = bh >> 4, h = bh & 15;
        const float* qbase = Q + ((size_t)(b * 8192 + m * 64)) * 1024 + h * 64;
        ushort* obase = Qf + ((size_t)bh * 128 + m) * 4224;
        #pragma unroll
        for (int k = 0; k < 4; ++k) {
            int idx = k * 256 + t;
            int l = idx >> 4, d4 = (idx & 15) * 4;
            float4 v = *(const float4*)(qbase + (size_t)l * 1024 + d4);
            ushort4 o; o.x = f2bf(v.x); o.y = f2bf(v.y); o.z = f2bf(v.z); o.w = f2bf(v.w);
            *(ushort4*)(obase + l * 64 + d4) = o;
            float pe = v.x + v.z, po = v.y + v.w;
            pe += __shfl_xor(pe, 1); po += __shfl_xor(po, 1);
            pe += __shfl_xor(pe, 2); po += __shfl_xor(po, 2);
            pe += __shfl_xor(pe, 4); po += __shfl_xor(po, 4);
            pe += __shfl_xor(pe, 8); po += __shfl_xor(po, 8);
            if ((t & 15) == 0) {
                ushort2 pp; pp.x = f2bf(pe * PSCALE); pp.y = f2bf(po * PSCALE);
                *(ushort2*)(obase + 4096 + 2 * l) = pp;
            }
        }
    }
}

// K -> Kf (plain bf16 + parity cols, [bh][n][4224]) and Kim = Gim.K ([bh][n][4096]).
__global__ __launch_bounds__(256) void k_prep_k(const float* __restrict__ K,
                                                const ushort* __restrict__ GimH,
                                                const ushort* __restrict__ GimL,
                                                ushort* __restrict__ Kf, ushort* __restrict__ Kim) {
    __shared__ ushort kb[64 * 72];
    int t = threadIdx.x;
    int lane = t & 63, wave = t >> 6;
    int wm = wave >> 1, wn = wave & 1;
    int row16 = lane & 15, quad = lane >> 4;
    int rrow = t >> 2, rcol = (t & 3) * 16;

    bf16x8 gih[2][2], gil[2][2];   // [nt][kk], constant per wave
    #pragma unroll
    for (int nt = 0; nt < 2; ++nt)
        #pragma unroll
        for (int kk = 0; kk < 2; ++kk) {
            int off = (wn * 32 + nt * 16 + row16) * 64 + kk * 32 + quad * 8;
            gih[nt][kk] = *(const bf16x8*)(GimH + off);
            gil[nt][kk] = *(const bf16x8*)(GimL + off);
        }

    for (int it = 0; it < 8; ++it) {
        int g = blockIdx.x * 8 + it;
        int bh = g >> 7, n = g & 127;
        int b = bh >> 4, h = bh & 15;
        const float* kbase = K + ((size_t)(b * 8192 + n * 64 + rrow)) * 1024 + h * 64 + rcol;
        ushort* kfrow = Kf + ((size_t)bh * 128 + n) * 4224;
        float pe = 0.f, po = 0.f;
        #pragma unroll
        for (int c = 0; c < 4; ++c) {
            float4 v = *(const float4*)(kbase + c * 4);
            ushort4 o; o.x = f2bf(v.x); o.y = f2bf(v.y); o.z = f2bf(v.z); o.w = f2bf(v.w);
            *(ushort4*)&kb[rrow * 72 + rcol + c * 4] = o;
            *(ushort4*)(kfrow + rrow * 64 + rcol + c * 4) = o;
            pe += v.x + v.z; po += v.y + v.w;
        }
        pe += __shfl_xor(pe, 1); po += __shfl_xor(po, 1);
        pe += __shfl_xor(pe, 2); po += __shfl_xor(po, 2);
        if ((t & 3) == 0) {
            ushort2 pp; pp.x = f2bf(pe * PSCALE); pp.y = f2bf(po * PSCALE);
            *(ushort2*)(kfrow + 4096 + 2 * rrow) = pp;
        }
        __syncthreads();

        f32x4 acc[2][2] = {};
        #pragma unroll
        for (int kk = 0; kk < 2; ++kk) {
            bf16x8 a[2];
            #pragma unroll
            for (int mt = 0; mt < 2; ++mt)
                a[mt] = *(const bf16x8*)&kb[(wm * 32 + mt * 16 + row16) * 72 + kk * 32 + quad * 8];
            #pragma unroll
            for (int mt = 0; mt < 2; ++mt)
                #pragma unroll
                for (int nt = 0; nt < 2; ++nt) {
                    acc[mt][nt] = __builtin_amdgcn_mfma_f32_16x16x32_bf16(a[mt], gih[nt][kk], acc[mt][nt], 0, 0, 0);
                    acc[mt][nt] = __builtin_amdgcn_mfma_f32_16x16x32_bf16(a[mt], gil[nt][kk], acc[mt][nt], 0, 0, 0);
                }
        }
        __syncthreads();
        #pragma unroll
        for (int mt = 0; mt < 2; ++mt)
            #pragma unroll
            for (int nt = 0; nt < 2; ++nt)
                #pragma unroll
                for (int i = 0; i < 4; ++i)
                    kb[(wm * 32 + mt * 16 + quad * 4 + i) * 72 + wn * 32 + nt * 16 + row16] = f2bf(acc[mt][nt][i]);
        __syncthreads();
        ushort* kimrow = Kim + ((size_t)bh * 128 + n) * 4096;
        *(uint4*)(kimrow + rrow * 64 + rcol)     = *(uint4*)&kb[rrow * 72 + rcol];
        *(uint4*)(kimrow + rrow * 64 + rcol + 8) = *(uint4*)&kb[rrow * 72 + rcol + 8];
        __syncthreads();
    }
}

// Sre/Sim partials. Grid (4 quadrants, 4 k-splits, 64 bh) = 1024 blocks.
// No LDS, no barriers: each wave streams its MFMA fragments straight from
// global (L1/L2 absorb the 2x wave duplication); compiler pipelines freely.
// Split s covers K-cols [s*1024, s*1024+1024); parity tiles 64,65 go to s=0,1.
__global__ __launch_bounds__(256, 4) void k_scores(const ushort* __restrict__ Qf,
                                                   const ushort* __restrict__ Kf,
                                                   const ushort* __restrict__ Kim,
                                                   float* __restrict__ SreP, float* __restrict__ SimP) {
    int qid = blockIdx.x;
    int s = blockIdx.y;
    int bh = blockIdx.z;
    int mh = qid >> 1, nh = qid & 1;
    int m0 = mh * 64, n0 = nh * 64;
    int t = threadIdx.x;
    int lane = t & 63, wave = t >> 6;
    int wm = wave >> 1, wn = wave & 1;
    int row16 = lane & 15, ql = lane >> 4;

    const ushort* aB = Qf + ((size_t)(bh * 128 + m0 + wm * 32 + row16)) * 4224 + ql * 8;
    const ushort* bB = Kf + ((size_t)(bh * 128 + n0 + wn * 32 + row16)) * 4224 + ql * 8;
    const ushort* iB = Kim + ((size_t)(bh * 128 + n0 + wn * 32 + row16)) * 4096 + ql * 8;

    f32x4 accre[2][2] = {};
    f32x4 accim[2][2] = {};
    int c0 = s * 1024;
    for (int k6 = 0; k6 < 16; ++k6) {
        int co = c0 + k6 * 64;
        bf16x8 a[2][2], b[2][2], bi[2][2];   // [kk][mt/nt]
        #pragma unroll
        for (int kk = 0; kk < 2; ++kk)
            #pragma unroll
            for (int x = 0; x < 2; ++x) {
                a[kk][x]  = *(const bf16x8*)(aB + (size_t)x * 16 * 4224 + co + kk * 32);
                b[kk][x]  = *(const bf16x8*)(bB + (size_t)x * 16 * 4224 + co + kk * 32);
                bi[kk][x] = *(const bf16x8*)(iB + (size_t)x * 16 * 4096 + co + kk * 32);
            }
        #pragma unroll
        for (int kk = 0; kk < 2; ++kk)
            #pragma unroll
            for (int mt = 0; mt < 2; ++mt)
                #pragma unroll
                for (int nt = 0; nt < 2; ++nt) {
                    accre[mt][nt] = __builtin_amdgcn_mfma_f32_16x16x32_bf16(a[kk][mt], b[kk][nt], accre[mt][nt], 0, 0, 0);
                    accim[mt][nt] = __builtin_amdgcn_mfma_f32_16x16x32_bf16(a[kk][mt], bi[kk][nt], accim[mt][nt], 0, 0, 0);
                }
    }
    if (s < 2) {   // parity tile 64+s, re-path only
        int co = (64 + s) * 64;
        bf16x8 a[2][2], b[2][2];
        #pragma unroll
        for (int kk = 0; kk < 2; ++kk)
            #pragma unroll
            for (int x = 0; x < 2; ++x) {
                a[kk][x] = *(const bf16x8*)(aB + (size_t)x * 16 * 4224 + co + kk * 32);
                b[kk][x] = *(const bf16x8*)(bB + (size_t)x * 16 * 4224 + co + kk * 32);
            }
        #pragma unroll
        for (int kk = 0; kk < 2; ++kk)
            #pragma unroll
            for (int mt = 0; mt < 2; ++mt)
                #pragma unroll
                for (int nt = 0; nt < 2; ++nt)
                    accre[mt][nt] = __builtin_amdgcn_mfma_f32_16x16x32_bf16(a[kk][mt], b[kk][nt], accre[mt][nt], 0, 0, 0);
    }
    float* sre = SreP + (size_t)s * 1048576 + (size_t)(bh * 128) * 128;
    float* sim = SimP + (size_t)s * 1048576 + (size_t)(bh * 128) * 128;
    #pragma unroll
    for (int mt = 0; mt < 2; ++mt)
        #pragma unroll
        for (int nt = 0; nt < 2; ++nt)
            #pragma unroll
            for (int i = 0; i < 4; ++i) {
                int r = m0 + wm * 32 + mt * 16 + ql * 4 + i;
                int c = n0 + wn * 32 + nt * 16 + row16;
                sre[r * 128 + c] = accre[mt][nt][i] * 0.0009765625f;   // 32/32768
                sim[r * 128 + c] = accim[mt][nt][i];
            }
}

// logits = |sum of partials|; softmax over n (128). One wave per row, 2 cols/lane.
__global__ __launch_bounds__(256) void k_softmax(const float* __restrict__ SreP,
                                                 const float* __restrict__ SimP,
                                                 ushort* __restrict__ A) {
    int t = threadIdx.x;
    int lane = t & 63, wave = t >> 6;
    for (int it = 0; it < 4; ++it) {
        int row = blockIdx.x * 16 + it * 4 + wave;
        size_t base = (size_t)row * 128 + lane * 2;
        float re0 = 0.f, re1 = 0.f, im0 = 0.f, im1 = 0.f;
        #pragma unroll
        for (int s = 0; s < 4; ++s) {
            float2 r = *(const float2*)(SreP + (size_t)s * 1048576 + base);
            float2 m2 = *(const float2*)(SimP + (size_t)s * 1048576 + base);
            re0 += r.x; re1 += r.y; im0 += m2.x; im1 += m2.y;
        }
        float lg0 = sqrtf(re0 * re0 + im0 * im0);
        float lg1 = sqrtf(re1 * re1 + im1 * im1);
        float mx = fmaxf(lg0, lg1);
        for (int o = 32; o > 0; o >>= 1) mx = fmaxf(mx, __shfl_xor(mx, o));
        float e0 = expf(lg0 - mx), e1 = expf(lg1 - mx);
        float sum = e0 + e1;
        for (int o = 32; o > 0; o >>= 1) sum += __shfl_xor(sum, o);
        float inv = 1.0f / sum;
        ushort2 o2; o2.x = f2bf(e0 * inv); o2.y = f2bf(e1 * inv);
        *(ushort2*)(A + base) = o2;
    }
}

// V[b, n*64+l, h, d] -> Vt[bh][l*64+d][n] bf16; 2048 blocks x 4 l each.
__global__ __launch_bounds__(256) void k_vt(const float* __restrict__ V, ushort* __restrict__ Vt) {
    __shared__ float tile[64 * 68];
    int lg = blockIdx.x, nh = blockIdx.y, bh = blockIdx.z;
    int b = bh >> 4, h = bh & 15;
    int t = threadIdx.x;
    int n = t & 63, dq = t >> 6;
    int d = t >> 2, cq = t & 3;
    for (int it = 0; it < 4; ++it) {
        int l = lg * 4 + it;
        const float* vbase = V + ((size_t)(b * 8192 + (nh * 64 + n) * 64 + l)) * 1024 + h * 64;
        #pragma unroll
        for (int r = 0; r < 4; ++r) {
            int d0 = r * 16 + dq * 4;
            float4 v = *(const float4*)(vbase + d0);
            tile[(d0 + 0) * 68 + n] = v.x; tile[(d0 + 1) * 68 + n] = v.y;
            tile[(d0 + 2) * 68 + n] = v.z; tile[(d0 + 3) * 68 + n] = v.w;
        }
        __syncthreads();
        __align__(16) ushort u[16];
        #pragma unroll
        for (int i = 0; i < 16; ++i) u[i] = f2bf(tile[d * 68 + cq * 16 + i]);
        ushort* ob = Vt + ((size_t)bh * 4096 + l * 64 + d) * 128 + nh * 64 + cq * 16;
        *(uint4*)(ob) = *(uint4*)&u[0];
        *(uint4*)(ob + 8) = *(uint4*)&u[8];
        __syncthreads();
    }
}

// Out[m, j=(l,d)] = sum_n A[m][n] * Vt[j][n]; stage A once, loop 4 j-tiles.
__global__ __launch_bounds__(256) void k_mix(const ushort* __restrict__ A,
                                             const ushort* __restrict__ Vt,
                                             float* __restrict__ Out) {
    __shared__ ushort At[128 * 136], Vtl[64 * 136];
    int grp = blockIdx.x, bh = blockIdx.y;
    int b = bh >> 4, h = bh & 15;
    int t = threadIdx.x;
    int lane = t & 63, wave = t >> 6;
    int row16 = lane & 15, quad = lane >> 4;
    const ushort* ag = A + (size_t)bh * 16384;
    #pragma unroll
    for (int p = 0; p < 8; ++p) {
        int idx = p * 256 + t;
        int row = idx >> 4, ch = idx & 15;
        *(uint4*)&At[row * 136 + ch * 8] = *(const uint4*)(ag + row * 128 + ch * 8);
    }
    for (int jt4 = 0; jt4 < 4; ++jt4) {
        int jt = grp * 4 + jt4;
        int j0 = jt * 64;
        const ushort* vg = Vt + ((size_t)bh * 4096 + j0) * 128;
        __syncthreads();
        #pragma unroll
        for (int p = 0; p < 4; ++p) {
            int idx = p * 256 + t;
            int row = idx >> 4, ch = idx & 15;
            *(uint4*)&Vtl[row * 136 + ch * 8] = *(const uint4*)(vg + (size_t)row * 128 + ch * 8);
        }
        __syncthreads();
        f32x4 acc[2][4] = {};
        #pragma unroll
        for (int kk = 0; kk < 4; ++kk) {
            bf16x8 a[2], bv[4];
            #pragma unroll
            for (int mt = 0; mt < 2; ++mt)
                a[mt] = *(const bf16x8*)&At[(wave * 32 + mt * 16 + row16) * 136 + kk * 32 + quad * 8];
            #pragma unroll
            for (int j2 = 0; j2 < 4; ++j2)
                bv[j2] = *(const bf16x8*)&Vtl[(j2 * 16 + row16) * 136 + kk * 32 + quad * 8];
            #pragma unroll
            for (int mt = 0; mt < 2; ++mt)
                #pragma unroll
                for (int j2 = 0; j2 < 4; ++j2)
                    acc[mt][j2] = __builtin_amdgcn_mfma_f32_16x16x32_bf16(a[mt], bv[j2], acc[mt][j2], 0, 0, 0);
        }
        #pragma unroll
        for (int mt = 0; mt < 2; ++mt)
            #pragma unroll
            for (int j2 = 0; j2 < 4; ++j2)
                #pragma unroll
                for (int i = 0; i < 4; ++i) {
                    int m = wave * 32 + mt * 16 + quad * 4 + i;
                    int dd = j2 * 16 + row16;
                    Out[((size_t)(b * 8192 + m * 64 + jt)) * 1024 + h * 64 + dd] = acc[mt][j2][i];
                }
    }
}

extern "C" void kernel_launch(void* const* d_in, const int* in_sizes, int n_in,
                              void* d_out, int out_size, void* d_ws, size_t ws_size,
                              hipStream_t stream) {
    const float* Q = (const float*)d_in[0];
    const float* K = (const float*)d_in[1];
    const float* V = (const float*)d_in[2];
    float* Out = (float*)d_out;
    char* ws = (char*)d_ws;
    // ws layout (total ~230 MiB):
    ushort* GimH = (ushort*)ws;                                  // 8 KB
    ushort* GimL = GimH + 4096;                                  // 8 KB
    float* SreP = (float*)(ws + 32768);                          // 16 MB (4 splits x 8192 x 128)
    float* SimP = SreP + (size_t)4 * 1048576;                    // 16 MB
    ushort* A   = (ushort*)(ws + 32768 + (size_t)2 * 16777216);  // 2 MB
    ushort* Qf  = A + 1048576;                                   // 66 MB (rows 4224)
    ushort* Kf  = Qf + (size_t)64 * 128 * 4224;                  // 66 MB
    ushort* Kim = Kf + (size_t)64 * 128 * 4224;                  // 64 MB (rows 4096)
    ushort* Vt  = Qf;  // alias: Qf dead after k_scores

    k_gmat<<<16, 256, 0, stream>>>(GimH, GimL);
    k_prep_q<<<1024, 256, 0, stream>>>(Q, Qf);
    k_prep_k<<<1024, 256, 0, stream>>>(K, GimH, GimL, Kf, Kim);
    k_scores<<<dim3(4, 4, 64), 256, 0, stream>>>(Qf, Kf, Kim, SreP, SimP);
    k_softmax<<<512, 256, 0, stream>>>(SreP, SimP, A);
    k_vt<<<dim3(16, 2, 64), 256, 0, stream>>>(V, Vt);
    k_mix<<<dim3(16, 64), 256, 0, stream>>>(A, Vt, Out);
}